// Round 1
// baseline (1939.420 us; speedup 1.0000x reference)
//
#include <hip/hip_runtime.h>
#include <math.h>

#define NIMG 96
#define RES_INV (1.0f / 262144.0f)   // 1 / (512*512), exact power of two

__device__ __forceinline__ int bin_of(float v) {
  float b = floorf((v + 1.0f) * 128.0f);
  b = fminf(fmaxf(b, 0.0f), 255.0f);
  return (int)b;
}

// ---------------- Kernel A: x-direction lifting (per row) -------------------
// src: (NIMG, H, 2*W2) row-major. Writes xe: (NIMG, H, W2).
// xo is consumed on the fly into delta stats. At level 0 also img stats.
__global__ void __launch_bounds__(256) klift_x(
    const float* __restrict__ src, float* __restrict__ xe_out,
    const float* __restrict__ kpx, const float* __restrict__ kux,
    const float* __restrict__ kcx, const float* __restrict__ krx,
    int H, int W2, int do_img,
    double* __restrict__ sumsq,          // [0]=img, [1]=delta
    unsigned* __restrict__ hist_img, unsigned* __restrict__ hist_delta)
{
  __shared__ float sxe[4][260];
  __shared__ float sxo[4][260];
  __shared__ unsigned shi[256];
  __shared__ unsigned shd[256];

  const int t = threadIdx.x, w = t >> 6, lane = t & 63;
  const int img = blockIdx.y;
  const int r = blockIdx.x * 4 + w;

  shd[t] = 0;
  if (do_img) shi[t] = 0;
  if (lane == 0) {
    sxe[w][0] = 0.f; sxe[w][W2 + 1] = 0.f;
    sxo[w][0] = 0.f; sxo[w][W2 + 1] = 0.f;
  }

  const float px0 = kpx[0], px1 = kpx[1], px2 = kpx[2];
  const float ux0 = kux[0], ux1 = kux[1], ux2 = kux[2];
  const float cx0 = kcx[0], cx1 = kcx[1], cx2 = kcx[2];
  const float rx0 = krx[0], rx1 = krx[1], rx2 = krx[2];

  const float* rowp = src + ((size_t)img * H + r) * (size_t)(2 * W2);
  float sqi = 0.f;
  __syncthreads();

  for (int c = lane; c < W2; c += 64) {
    float2 v = *(const float2*)(rowp + 2 * c);
    sxe[w][c + 1] = v.x; sxo[w][c + 1] = v.y;
    if (do_img) {
      sqi += v.x * v.x + v.y * v.y;
      atomicAdd(&shi[bin_of(v.x)], 1u);
      atomicAdd(&shi[bin_of(v.y)], 1u);
    }
  }
  __syncthreads();
  for (int c = lane; c < W2; c += 64)
    sxo[w][c + 1] -= px0 * sxe[w][c] + px1 * sxe[w][c + 1] + px2 * sxe[w][c + 2];
  __syncthreads();
  for (int c = lane; c < W2; c += 64)
    sxe[w][c + 1] += ux0 * sxo[w][c] + ux1 * sxo[w][c + 1] + ux2 * sxo[w][c + 2];
  __syncthreads();
  for (int c = lane; c < W2; c += 64)
    sxo[w][c + 1] -= cx0 * sxe[w][c] + cx1 * sxe[w][c + 1] + cx2 * sxe[w][c + 2];
  __syncthreads();
  for (int c = lane; c < W2; c += 64)
    sxe[w][c + 1] += rx0 * sxo[w][c] + rx1 * sxo[w][c + 1] + rx2 * sxo[w][c + 2];
  __syncthreads();

  float* orow = xe_out + ((size_t)img * H + r) * (size_t)W2;
  float sqd = 0.f;
  for (int c = lane; c < W2; c += 64) {
    float xo = sxo[w][c + 1];
    float d = fmodf(xo + 1.0f, 2.0f) - 1.0f;
    sqd += d * d;
    if (d >= -1.0f && d <= 1.0f) atomicAdd(&shd[bin_of(d)], 1u);
    orow[c] = sxe[w][c + 1];
  }

  for (int off = 32; off; off >>= 1) {
    sqd += __shfl_down(sqd, off);
    if (do_img) sqi += __shfl_down(sqi, off);
  }
  if (lane == 0) {
    atomicAdd(&sumsq[1], (double)sqd);
    if (do_img) atomicAdd(&sumsq[0], (double)sqi);
  }
  __syncthreads();
  unsigned hd = shd[t];
  if (hd) atomicAdd(&hist_delta[img * 256 + t], hd);
  if (do_img) {
    unsigned hi = shi[t];
    if (hi) atomicAdd(&hist_img[img * 256 + t], hi);
  }
}

// ---------------- Kernel B: y-direction lifting (per column stripe) ---------
// xe: (NIMG, 2*H2, W2). Writes ye: (NIMG, H2, W2). yo -> stats.
// Block handles C columns x full height of one image, all in LDS.
__global__ void __launch_bounds__(256) klift_y(
    const float* __restrict__ xe, float* __restrict__ ye_out,
    const float* __restrict__ kpy, const float* __restrict__ kuy,
    const float* __restrict__ kcy, const float* __restrict__ kry,
    int H2, int W2, int C, int use_uy, int add_ye,
    double* __restrict__ sumsq, unsigned* __restrict__ hist_delta)
{
  __shared__ float sye[8256];   // (H2max+2)*Cmax = 258*32
  __shared__ float syo[8256];
  __shared__ unsigned shd[256];

  const int t = threadIdx.x;
  const int img = blockIdx.y;
  const int c = t % C;
  const int rt = t / C;
  const int R = 256 / C;
  const int c0 = blockIdx.x * C;

  shd[t] = 0;
  if (t < C) {
    sye[t] = 0.f; sye[(H2 + 1) * C + t] = 0.f;
    syo[t] = 0.f; syo[(H2 + 1) * C + t] = 0.f;
  }
  __syncthreads();

  const float py0 = kpy[0], py1 = kpy[1], py2 = kpy[2];
  const float uy0 = kuy[0], uy1 = kuy[1], uy2 = kuy[2];
  const float cy0 = kcy[0], cy1 = kcy[1], cy2 = kcy[2];
  const float ry0 = kry[0], ry1 = kry[1], ry2 = kry[2];

  const float* base = xe + (size_t)img * (2 * H2) * W2 + c0;
  for (int h = rt; h < 2 * H2; h += R) {
    float v = base[(size_t)h * W2 + c];
    int i = ((h >> 1) + 1) * C + c;
    if (h & 1) syo[i] = v; else sye[i] = v;
  }
  __syncthreads();

  for (int r = rt; r < H2; r += R) {
    int i = (r + 1) * C + c;
    syo[i] -= py0 * sye[i - C] + py1 * sye[i] + py2 * sye[i + C];
  }
  __syncthreads();
  if (use_uy) {
    for (int r = rt; r < H2; r += R) {
      int i = (r + 1) * C + c;
      sye[i] += uy0 * syo[i - C] + uy1 * syo[i] + uy2 * syo[i + C];
    }
    __syncthreads();
  }
  for (int r = rt; r < H2; r += R) {
    int i = (r + 1) * C + c;
    syo[i] -= cy0 * sye[i - C] + cy1 * sye[i] + cy2 * sye[i + C];
  }
  __syncthreads();
  for (int r = rt; r < H2; r += R) {
    int i = (r + 1) * C + c;
    sye[i] += ry0 * syo[i - C] + ry1 * syo[i] + ry2 * syo[i + C];
  }
  __syncthreads();

  float sqd = 0.f;
  float* obase = ye_out + (size_t)img * H2 * W2 + c0;
  for (int r = rt; r < H2; r += R) {
    int i = (r + 1) * C + c;
    float yo = syo[i];
    float d = fmodf(yo + 1.0f, 2.0f) - 1.0f;
    sqd += d * d;
    if (d >= -1.0f && d <= 1.0f) atomicAdd(&shd[bin_of(d)], 1u);
    float yev = sye[i];
    if (add_ye) {
      float d2 = fmodf(yev + 1.0f, 2.0f) - 1.0f;
      sqd += d2 * d2;
      if (d2 >= -1.0f && d2 <= 1.0f) atomicAdd(&shd[bin_of(d2)], 1u);
    }
    obase[(size_t)r * W2 + c] = yev;
  }

  for (int off = 32; off; off >>= 1) sqd += __shfl_down(sqd, off);
  if ((t & 63) == 0) atomicAdd(&sumsq[1], (double)sqd);
  __syncthreads();
  unsigned hd = shd[t];
  if (hd) atomicAdd(&hist_delta[img * 256 + t], hd);
}

// ---------------- Final reduction: entropies + losses -----------------------
__global__ void __launch_bounds__(256) kfinal(
    const double* __restrict__ sumsq,
    const unsigned* __restrict__ hist_img,
    const unsigned* __restrict__ hist_delta,
    float* __restrict__ out)
{
  __shared__ double sI[256], sD[256];
  const int t = threadIdx.x;
  double entI = 0.0, entD = 0.0;
  for (int img = 0; img < NIMG; ++img) {
    unsigned ci = hist_img[img * 256 + t];
    if (ci) { float p = (float)ci * RES_INV; entI += (double)(-p * log2f(p)); }
    unsigned cd = hist_delta[img * 256 + t];
    if (cd) { float p = (float)cd * RES_INV; entD += (double)(-p * log2f(p)); }
  }
  sI[t] = entI; sD[t] = entD;
  __syncthreads();
  for (int s = 128; s; s >>= 1) {
    if (t < s) { sI[t] += sI[t + s]; sD[t] += sD[t + s]; }
    __syncthreads();
  }
  if (t == 0) {
    const double tot = (double)NIMG * 262144.0;
    out[0] = (float)(255.0 * sqrt(sumsq[1] / tot));  // loss1 (deltas)
    out[1] = (float)(255.0 * sqrt(sumsq[0] / tot));  // loss0 (img)
    out[2] = (float)(sI[0] / (8.0 * NIMG));          // invCR0
    out[3] = (float)(sD[0] / (8.0 * NIMG));          // invCR1
  }
}

extern "C" void kernel_launch(void* const* d_in, const int* in_sizes, int n_in,
                              void* d_out, int out_size, void* d_ws, size_t ws_size,
                              hipStream_t stream)
{
  const float* x  = (const float*)d_in[0];
  const float* px = (const float*)d_in[1];
  const float* ux = (const float*)d_in[2];
  const float* cx = (const float*)d_in[3];
  const float* rx = (const float*)d_in[4];
  const float* py = (const float*)d_in[5];
  const float* uy = (const float*)d_in[6];
  const float* cy = (const float*)d_in[7];
  const float* ry = (const float*)d_in[8];
  float* out = (float*)d_out;

  char* ws = (char*)d_ws;
  // layout: [2 doubles][hist_img 96*256 u32][hist_delta 96*256 u32] then buffers
  double*   sumsq      = (double*)ws;
  unsigned* hist_img   = (unsigned*)(ws + 16);
  unsigned* hist_delta = (unsigned*)(ws + 16 + NIMG * 256 * 4);
  float* buf0 = (float*)(ws + (1 << 18));                        // xe, <=48MB
  float* buf1 = (float*)(ws + (1 << 18) + ((size_t)48 << 20));   // ye, <=24MB

  hipMemsetAsync(ws, 0, 16 + 2 * NIMG * 256 * 4, stream);

  const float* cur = x;
  for (int lvl = 0; lvl < 5; ++lvl) {
    int H = 512 >> lvl, W2 = 256 >> lvl, H2 = H >> 1;
    dim3 gA(H / 4, NIMG);
    klift_x<<<gA, 256, 0, stream>>>(cur, buf0, px, ux, cx, rx, H, W2, lvl == 0,
                                    sumsq, hist_img, hist_delta);
    int C = (W2 >= 32) ? 32 : W2;
    dim3 gB(W2 / C, NIMG);
    klift_y<<<gB, 256, 0, stream>>>(buf0, buf1, py, uy, cy, ry, H2, W2, C,
                                    lvl < 2, lvl == 4, sumsq, hist_delta);
    cur = buf1;
  }
  kfinal<<<1, 256, 0, stream>>>(sumsq, hist_img, hist_delta, out);
}

// Round 2
// 217.297 us; speedup vs baseline: 8.9252x; 8.9252x over previous
//
#include <hip/hip_runtime.h>
#include <math.h>

#define NIMG 96
#define NSLOT 1024
#define RES_INV (1.0f / 262144.0f)   // 1 / (512*512), exact power of two

__device__ __forceinline__ int bin_of(float v) {
  float b = floorf((v + 1.0f) * 128.0f);
  b = fminf(fmaxf(b, 0.0f), 255.0f);
  return (int)b;
}

// ---------------- Kernel A: x-direction lifting (per row) -------------------
// src: (NIMG, H, 2*W2) row-major. Writes xe: (NIMG, H, W2).
// xo is consumed on the fly into delta stats. At level 0 also img stats.
// partial: [0..NSLOT) img sumsq, [NSLOT..2*NSLOT) delta sumsq.
__global__ void __launch_bounds__(256) klift_x(
    const float* __restrict__ src, float* __restrict__ xe_out,
    const float* __restrict__ kpx, const float* __restrict__ kux,
    const float* __restrict__ kcx, const float* __restrict__ krx,
    int H, int W2, int do_img,
    double* __restrict__ partial,
    unsigned* __restrict__ hist_img, unsigned* __restrict__ hist_delta)
{
  __shared__ float sxe[4][260];
  __shared__ float sxo[4][260];
  __shared__ unsigned shi[256];
  __shared__ unsigned shd[256];

  const int t = threadIdx.x, w = t >> 6, lane = t & 63;
  const int img = blockIdx.y;
  const int r = blockIdx.x * 4 + w;

  shd[t] = 0;
  if (do_img) shi[t] = 0;
  if (lane == 0) {
    sxe[w][0] = 0.f; sxe[w][W2 + 1] = 0.f;
    sxo[w][0] = 0.f; sxo[w][W2 + 1] = 0.f;
  }

  const float px0 = kpx[0], px1 = kpx[1], px2 = kpx[2];
  const float ux0 = kux[0], ux1 = kux[1], ux2 = kux[2];
  const float cx0 = kcx[0], cx1 = kcx[1], cx2 = kcx[2];
  const float rx0 = krx[0], rx1 = krx[1], rx2 = krx[2];

  const float* rowp = src + ((size_t)img * H + r) * (size_t)(2 * W2);
  float sqi = 0.f;
  __syncthreads();

  for (int c = lane; c < W2; c += 64) {
    float2 v = *(const float2*)(rowp + 2 * c);
    sxe[w][c + 1] = v.x; sxo[w][c + 1] = v.y;
    if (do_img) {
      sqi += v.x * v.x + v.y * v.y;
      atomicAdd(&shi[bin_of(v.x)], 1u);
      atomicAdd(&shi[bin_of(v.y)], 1u);
    }
  }
  __syncthreads();
  for (int c = lane; c < W2; c += 64)
    sxo[w][c + 1] -= px0 * sxe[w][c] + px1 * sxe[w][c + 1] + px2 * sxe[w][c + 2];
  __syncthreads();
  for (int c = lane; c < W2; c += 64)
    sxe[w][c + 1] += ux0 * sxo[w][c] + ux1 * sxo[w][c + 1] + ux2 * sxo[w][c + 2];
  __syncthreads();
  for (int c = lane; c < W2; c += 64)
    sxo[w][c + 1] -= cx0 * sxe[w][c] + cx1 * sxe[w][c + 1] + cx2 * sxe[w][c + 2];
  __syncthreads();
  for (int c = lane; c < W2; c += 64)
    sxe[w][c + 1] += rx0 * sxo[w][c] + rx1 * sxo[w][c + 1] + rx2 * sxo[w][c + 2];
  __syncthreads();

  float* orow = xe_out + ((size_t)img * H + r) * (size_t)W2;
  float sqd = 0.f;
  for (int c = lane; c < W2; c += 64) {
    float xo = sxo[w][c + 1];
    float d = fmodf(xo + 1.0f, 2.0f) - 1.0f;
    sqd += d * d;
    if (d >= -1.0f && d <= 1.0f) atomicAdd(&shd[bin_of(d)], 1u);
    orow[c] = sxe[w][c + 1];
  }

  for (int off = 32; off; off >>= 1) {
    sqd += __shfl_down(sqd, off);
    if (do_img) sqi += __shfl_down(sqi, off);
  }
  if (lane == 0) {
    const int bid = blockIdx.x + blockIdx.y * gridDim.x;
    const int slot = (bid * 4 + w) & (NSLOT - 1);
    atomicAdd(&partial[NSLOT + slot], (double)sqd);
    if (do_img) atomicAdd(&partial[slot], (double)sqi);
  }
  __syncthreads();
  unsigned hd = shd[t];
  if (hd) atomicAdd(&hist_delta[img * 256 + t], hd);
  if (do_img) {
    unsigned hi = shi[t];
    if (hi) atomicAdd(&hist_img[img * 256 + t], hi);
  }
}

// ---------------- Kernel B: y-direction lifting (per column stripe) ---------
// xe: (NIMG, 2*H2, W2). Writes ye: (NIMG, H2, W2). yo -> stats.
// Block handles C columns x full height of one image, all in LDS.
__global__ void __launch_bounds__(256) klift_y(
    const float* __restrict__ xe, float* __restrict__ ye_out,
    const float* __restrict__ kpy, const float* __restrict__ kuy,
    const float* __restrict__ kcy, const float* __restrict__ kry,
    int H2, int W2, int C, int use_uy, int add_ye,
    double* __restrict__ partial, unsigned* __restrict__ hist_delta)
{
  __shared__ float sye[8256];   // (H2max+2)*Cmax = 258*32
  __shared__ float syo[8256];
  __shared__ unsigned shd[256];

  const int t = threadIdx.x;
  const int img = blockIdx.y;
  const int c = t % C;
  const int rt = t / C;
  const int R = 256 / C;
  const int c0 = blockIdx.x * C;

  shd[t] = 0;
  if (t < C) {
    sye[t] = 0.f; sye[(H2 + 1) * C + t] = 0.f;
    syo[t] = 0.f; syo[(H2 + 1) * C + t] = 0.f;
  }
  __syncthreads();

  const float py0 = kpy[0], py1 = kpy[1], py2 = kpy[2];
  const float uy0 = kuy[0], uy1 = kuy[1], uy2 = kuy[2];
  const float cy0 = kcy[0], cy1 = kcy[1], cy2 = kcy[2];
  const float ry0 = kry[0], ry1 = kry[1], ry2 = kry[2];

  const float* base = xe + (size_t)img * (2 * H2) * W2 + c0;
  for (int h = rt; h < 2 * H2; h += R) {
    float v = base[(size_t)h * W2 + c];
    int i = ((h >> 1) + 1) * C + c;
    if (h & 1) syo[i] = v; else sye[i] = v;
  }
  __syncthreads();

  for (int r = rt; r < H2; r += R) {
    int i = (r + 1) * C + c;
    syo[i] -= py0 * sye[i - C] + py1 * sye[i] + py2 * sye[i + C];
  }
  __syncthreads();
  if (use_uy) {
    for (int r = rt; r < H2; r += R) {
      int i = (r + 1) * C + c;
      sye[i] += uy0 * syo[i - C] + uy1 * syo[i] + uy2 * syo[i + C];
    }
    __syncthreads();
  }
  for (int r = rt; r < H2; r += R) {
    int i = (r + 1) * C + c;
    syo[i] -= cy0 * sye[i - C] + cy1 * sye[i] + cy2 * sye[i + C];
  }
  __syncthreads();
  for (int r = rt; r < H2; r += R) {
    int i = (r + 1) * C + c;
    sye[i] += ry0 * syo[i - C] + ry1 * syo[i] + ry2 * syo[i + C];
  }
  __syncthreads();

  float sqd = 0.f;
  float* obase = ye_out + (size_t)img * H2 * W2 + c0;
  for (int r = rt; r < H2; r += R) {
    int i = (r + 1) * C + c;
    float yo = syo[i];
    float d = fmodf(yo + 1.0f, 2.0f) - 1.0f;
    sqd += d * d;
    if (d >= -1.0f && d <= 1.0f) atomicAdd(&shd[bin_of(d)], 1u);
    float yev = sye[i];
    if (add_ye) {
      float d2 = fmodf(yev + 1.0f, 2.0f) - 1.0f;
      sqd += d2 * d2;
      if (d2 >= -1.0f && d2 <= 1.0f) atomicAdd(&shd[bin_of(d2)], 1u);
    }
    obase[(size_t)r * W2 + c] = yev;
  }

  for (int off = 32; off; off >>= 1) sqd += __shfl_down(sqd, off);
  if ((t & 63) == 0) {
    const int bid = blockIdx.x + blockIdx.y * gridDim.x;
    const int slot = (bid * 4 + (t >> 6)) & (NSLOT - 1);
    atomicAdd(&partial[NSLOT + slot], (double)sqd);
  }
  __syncthreads();
  unsigned hd = shd[t];
  if (hd) atomicAdd(&hist_delta[img * 256 + t], hd);
}

// ---------------- Final reduction: entropies + losses -----------------------
__global__ void __launch_bounds__(256) kfinal(
    const double* __restrict__ partial,
    const unsigned* __restrict__ hist_img,
    const unsigned* __restrict__ hist_delta,
    float* __restrict__ out)
{
  __shared__ double sI[256], sD[256], sPi[256], sPd[256];
  const int t = threadIdx.x;
  double entI = 0.0, entD = 0.0;
  for (int img = 0; img < NIMG; ++img) {
    unsigned ci = hist_img[img * 256 + t];
    if (ci) { float p = (float)ci * RES_INV; entI += (double)(-p * log2f(p)); }
    unsigned cd = hist_delta[img * 256 + t];
    if (cd) { float p = (float)cd * RES_INV; entD += (double)(-p * log2f(p)); }
  }
  double pi = 0.0, pd = 0.0;
  for (int s = t; s < NSLOT; s += 256) {
    pi += partial[s];
    pd += partial[NSLOT + s];
  }
  sI[t] = entI; sD[t] = entD; sPi[t] = pi; sPd[t] = pd;
  __syncthreads();
  for (int s = 128; s; s >>= 1) {
    if (t < s) {
      sI[t] += sI[t + s]; sD[t] += sD[t + s];
      sPi[t] += sPi[t + s]; sPd[t] += sPd[t + s];
    }
    __syncthreads();
  }
  if (t == 0) {
    const double tot = (double)NIMG * 262144.0;
    out[0] = (float)(255.0 * sqrt(sPd[0] / tot));  // loss1 (deltas)
    out[1] = (float)(255.0 * sqrt(sPi[0] / tot));  // loss0 (img)
    out[2] = (float)(sI[0] / (8.0 * NIMG));        // invCR0
    out[3] = (float)(sD[0] / (8.0 * NIMG));        // invCR1
  }
}

extern "C" void kernel_launch(void* const* d_in, const int* in_sizes, int n_in,
                              void* d_out, int out_size, void* d_ws, size_t ws_size,
                              hipStream_t stream)
{
  const float* x  = (const float*)d_in[0];
  const float* px = (const float*)d_in[1];
  const float* ux = (const float*)d_in[2];
  const float* cx = (const float*)d_in[3];
  const float* rx = (const float*)d_in[4];
  const float* py = (const float*)d_in[5];
  const float* uy = (const float*)d_in[6];
  const float* cy = (const float*)d_in[7];
  const float* ry = (const float*)d_in[8];
  float* out = (float*)d_out;

  char* ws = (char*)d_ws;
  // layout: [partial 2*NSLOT doubles][hist_img 96*256 u32][hist_delta 96*256 u32][buffers]
  double*   partial    = (double*)ws;
  unsigned* hist_img   = (unsigned*)(ws + 2 * NSLOT * 8);
  unsigned* hist_delta = (unsigned*)(ws + 2 * NSLOT * 8 + NIMG * 256 * 4);
  float* buf0 = (float*)(ws + (1 << 18));                        // xe, <=48MB
  float* buf1 = (float*)(ws + (1 << 18) + ((size_t)48 << 20));   // ye, <=24MB

  hipMemsetAsync(ws, 0, 2 * NSLOT * 8 + 2 * NIMG * 256 * 4, stream);

  const float* cur = x;
  for (int lvl = 0; lvl < 5; ++lvl) {
    int H = 512 >> lvl, W2 = 256 >> lvl, H2 = H >> 1;
    dim3 gA(H / 4, NIMG);
    klift_x<<<gA, 256, 0, stream>>>(cur, buf0, px, ux, cx, rx, H, W2, lvl == 0,
                                    partial, hist_img, hist_delta);
    int C = (W2 >= 32) ? 32 : W2;
    dim3 gB(W2 / C, NIMG);
    klift_y<<<gB, 256, 0, stream>>>(buf0, buf1, py, uy, cy, ry, H2, W2, C,
                                    lvl < 2, lvl == 4, partial, hist_delta);
    cur = buf1;
  }
  kfinal<<<1, 256, 0, stream>>>(partial, hist_img, hist_delta, out);
}